// Round 14
// baseline (229.741 us; speedup 1.0000x reference)
//
#include <hip/hip_runtime.h>
#include <hip/hip_bf16.h>

#define DEV __device__ __forceinline__

typedef __attribute__((ext_vector_type(8))) short bhalf8;   // 8 bf16 (4 VGPR)
typedef __attribute__((ext_vector_type(4))) float f32x4;    // MFMA C/D
typedef __attribute__((ext_vector_type(4))) float f4v;
typedef __attribute__((ext_vector_type(4))) unsigned uint4v;
typedef __attribute__((ext_vector_type(2))) unsigned uint2v;

// ---- workspace layout (bytes) ----
constexpr size_t OFF_WE1   = 0;         // [128][512] bf16
constexpr size_t OFF_WE2   = 131072;
constexpr size_t OFF_WCA   = 262144;    // [32][256] bf16
constexpr size_t OFF_WCV   = 278528;
constexpr size_t OFF_WCOMB = 294912;    // [256] f32 = W_r2 @ W_r1
constexpr size_t OFF_BC    = 295936;    // scalar f32 = b_r1.W_r2 + b_r2

DEV short f2bf(float f) {               // RNE float->bf16 bits
    __hip_bfloat16 h = __float2bfloat16(f);
    return __builtin_bit_cast(short, h);
}
DEV float bf2f(short s) {
    unsigned u = ((unsigned)(unsigned short)s) << 16;
    return __builtin_bit_cast(float, u);
}
DEV unsigned pk2bf(float lo, float hi) {  // word = bits(hi)<<16 | bits(lo)
    unsigned ul = (unsigned)(unsigned short)f2bf(lo);
    unsigned uh = (unsigned)(unsigned short)f2bf(hi);
    return (uh << 16) | ul;
}
DEV float fexp2(float x) { float r; asm("v_exp_f32 %0, %1" : "=v"(r) : "v"(x)); return r; }
DEV float frcp (float x) { float r; asm("v_rcp_f32 %0, %1" : "=v"(r) : "v"(x)); return r; }

#define WFENCE() asm volatile("s_waitcnt lgkmcnt(0)" ::: "memory")
#define MFMA(a,b,c) __builtin_amdgcn_mfma_f32_16x16x32_bf16(a,b,c,0,0,0)

// z/H tile row pitch: 80 B (20-bank step) -> <=2-way bank aliasing (free).
// R12: z stripes are PER-MOD only (batch-sequential round-trip) -> LDS
// 66560 -> 46080 B -> 3 blocks/CU (was 2). Occupancy is the R11-indicted
// bottleneck (42%, both pipes <55% busy).
constexpr int ZPITCH = 80;
constexpr int ZSTRIPE = 128 * ZPITCH;   // per mod stripe: 10240 B
constexpr int ZBASE  = 16384;           // z region after G region

// ---------------- prep: bf16 weights + collapsed regressor ----------------
__global__ void k_prep(const float* __restrict__ We1, const float* __restrict__ We2,
                       const float* __restrict__ Wca, const float* __restrict__ Wcv,
                       const float* __restrict__ Wr1, const float* __restrict__ br1,
                       const float* __restrict__ Wr2, const float* __restrict__ br2,
                       char* __restrict__ ws)
{
    int idx = blockIdx.x * 256 + threadIdx.x;      // 65536 threads
    short* we1 = (short*)(ws + OFF_WE1);
    short* we2 = (short*)(ws + OFF_WE2);
    short* wca = (short*)(ws + OFF_WCA);
    short* wcv = (short*)(ws + OFF_WCV);
    float* wcomb = (float*)(ws + OFF_WCOMB);
    float* bcp   = (float*)(ws + OFF_BC);

    we1[idx] = f2bf(We1[idx]);
    we2[idx] = f2bf(We2[idx]);
    if (idx < 8192) { wca[idx] = f2bf(Wca[idx]); wcv[idx] = f2bf(Wcv[idx]); }
    if (idx < 256) {                    // wcomb[j] = sum_q Wr2[q]*Wr1[q][j]
        float s = 0.0f;
        for (int q = 0; q < 128; ++q) s += Wr2[q] * Wr1[q * 256 + idx];
        wcomb[idx] = s;
    }
    if (idx == 0) {                     // bc = br1 . Wr2 + br2
        float s = br2[0];
        for (int q = 0; q < 128; ++q) s += br1[q] * Wr2[q];
        bcp[0] = s;
    }
}

// -------- fully fused, 2 batches/block: encoder + co-attn + regressor --------
// 512 threads (8 waves). E1: wave -> (mod = w>>2, 32 cols, both batches).
// M/H: wave -> (mod = w>>2, rows (w&3)*32..+31); mT MFMAs batch-interleaved,
// z LDS round-trip batch-SEQUENTIAL on a shared per-mod stripe (halves LDS).
__global__ __launch_bounds__(512, 6) void k_fused(
    const float* __restrict__ f1,   const float* __restrict__ f2,
    const float* __restrict__ be1,  const float* __restrict__ be2,
    const float* __restrict__ waffa,const float* __restrict__ waffv,
    const float* __restrict__ Wa,   const float* __restrict__ Wv,
    const float* __restrict__ Wha,  const float* __restrict__ Whv,
    const char* __restrict__ ws, float* __restrict__ out)
{
    // [0,16K): G (after E1); during E0/E1 the f-stage overlay uses [0,32K)
    // [16K, 16K+2*10240): z/H stripes per mod (shared by both batches)
    __shared__ __align__(16) char  s_z[ZBASE + 2 * ZSTRIPE];   // 36864 B
    __shared__ __align__(16) short s_At[2][2][128][8];// [batch][mod] av bf16 [i][t]
    __shared__ float s_waff[2][8][8];
    __shared__ float s_red[8][2][8];

    short* sG = (short*)s_z;                          // [b*2+m][256][8] after E1

    const int tid = threadIdx.x;
    const int w = tid >> 6, l = tid & 63, lr = l & 15, lg = l >> 4;
    const int mod = w >> 2;              // wave's modality
    const int wn  = w & 3;               // wave index within modality group
    const bool k8 = (lg == 0);           // lanes carrying the real K=8 slice

    const short* we   = (const short*)(ws + (mod ? OFF_WE2 : OFF_WE1));
    const short* wca  = (const short*)(ws + (mod ? OFF_WCV : OFF_WCA));
    const float* wcomb= (const float*)(ws + OFF_WCOMB);
    const float* be   = mod ? be2 : be1;
    const float* wha  = mod ? Whv : Wha;
    const float* wa   = mod ? Wv  : Wa;

    const bhalf8 zf8 = {0,0,0,0,0,0,0,0};
    const f32x4  zf4 = {0.f,0.f,0.f,0.f};

    // ---- E0: stage f rows (2 batches x 2 mods) bf16 into s_z, 8KB stripes ----
    {
        int row = tid >> 6, k0 = (tid & 63) * 8;
        #pragma unroll
        for (int b = 0; b < 2; ++b)
        #pragma unroll
        for (int m = 0; m < 2; ++m) {
            const float* fp = (m ? f2 : f1)
                + ((long)blockIdx.x * 2 + b) * 4096 + row * 512 + k0;
            f4v a0 = *(const f4v*)fp;
            f4v a1 = *(const f4v*)(fp + 4);
            uint4v u;
            u[0] = pk2bf(a0[0], a0[1]); u[1] = pk2bf(a0[2], a0[3]);
            u[2] = pk2bf(a1[0], a1[1]); u[3] = pk2bf(a1[2], a1[3]);
            int off = ((b*2+m) * 8192 + row * 1024 + k0 * 2) ^ (row << 4);
            *(uint4v*)(s_z + off) = u;
        }
        if (tid < 128) {
            const float* src = (tid < 64) ? waffa : waffv;
            s_waff[tid >> 6][(tid >> 3) & 7][tid & 7] = src[tid & 63];
        }
    }
    __syncthreads();

    // ---- E1: encoder GEMM, both batches share each We fragment ----
    {
        f32x4 acc[2][2] = {{zf4, zf4}, {zf4, zf4}};   // [batch][nt]
        const int r8 = lr & 7;
        const int fs0 = (0*2 + mod) * 8192 + r8 * 1024;
        const int fs1 = (1*2 + mod) * 8192 + r8 * 1024;
        const int fswz = r8 << 4;
        const short* wp0 = we + (wn*32 + lr) * 512 + lg * 8;
        const short* wp1 = wp0 + 16 * 512;
        bhalf8 bw0 = *(const bhalf8*)wp0;             // prefetched fragment
        bhalf8 bw1 = *(const bhalf8*)wp1;
        #pragma unroll
        for (int ks = 0; ks < 16; ++ks) {
            int fo = (ks*64 + lg*16) ^ fswz;
            bhalf8 af0 = *(const bhalf8*)(s_z + fs0 + fo);
            bhalf8 af1 = *(const bhalf8*)(s_z + fs1 + fo);
            bhalf8 nb0 = bw0, nb1 = bw1;
            if (ks < 15) {                            // software prefetch ks+1
                nb0 = *(const bhalf8*)(wp0 + (ks+1) * 32);
                nb1 = *(const bhalf8*)(wp1 + (ks+1) * 32);
            }
            acc[0][0] = MFMA(af0, bw0, acc[0][0]);
            acc[0][1] = MFMA(af0, bw1, acc[0][1]);
            acc[1][0] = MFMA(af1, bw0, acc[1][0]);
            acc[1][1] = MFMA(af1, bw1, acc[1][1]);
            bw0 = nb0; bw1 = nb1;
        }
        if (lg < 2) {                                 // t = lg*4+r in 0..7
            #pragma unroll
            for (int b = 0; b < 2; ++b)
            #pragma unroll
            for (int nt = 0; nt < 2; ++nt) {
                int n = wn*32 + nt*16 + lr;
                float bias = be[n];
                uint2v u;
                u[0] = pk2bf(acc[b][nt][0]+bias, acc[b][nt][1]+bias);
                u[1] = pk2bf(acc[b][nt][2]+bias, acc[b][nt][3]+bias);
                *(uint2v*)&s_At[b][mod][n][lg*4] = u;
            }
        }
    }
    __syncthreads();   // f-stage dead; G + z regions become writable

    // ---- G: G' = (Waff @ av) * (scale*2*log2e)  [tanh prefold] ----
    {
        const float kfold = (1.0f / 16.0f) * 2.0f * 1.44269504088896340736f;
        #pragma unroll
        for (int u = 0; u < 2; ++u) {
            int idx = tid + 512 * u;                  // 0..1023
            int b = idx >> 9, m = (idx >> 8) & 1, j = idx & 255;
            const short* avp = (j < 128) ? &s_At[b][0][j][0]
                                         : &s_At[b][1][j - 128][0];
            bhalf8 avv = *(const bhalf8*)avp;
            float avf[8];
            #pragma unroll
            for (int t = 0; t < 8; ++t) avf[t] = bf2f(avv[t]);
            float g[8] = {0,0,0,0,0,0,0,0};
            #pragma unroll
            for (int t = 0; t < 8; ++t)
                #pragma unroll
                for (int p = 0; p < 8; ++p) g[p] += s_waff[m][p][t] * avf[t];
            bhalf8 gv;
            #pragma unroll
            for (int p = 0; p < 8; ++p) gv[p] = f2bf(g[p] * kfold);
            *(bhalf8*)(sG + ((b*2+m)*256 + j)*8) = gv;
        }
    }
    __syncthreads();

    // ---- M/H: wave owns (mod, rows rowbase..+31); shared per-mod z stripe ----
    const int rowbase = wn * 32;
    char* zs = s_z + ZBASE + mod * ZSTRIPE;           // shared stripe (both b)
    float pacc[2] = {0.0f, 0.0f};

    bhalf8 atf[2][2];                                 // [batch][mt]
    #pragma unroll
    for (int b = 0; b < 2; ++b)
    #pragma unroll
    for (int mt = 0; mt < 2; ++mt)
        atf[b][mt] = k8 ? *(const bhalf8*)&s_At[b][mod][rowbase + mt*16 + lr][0]
                        : zf8;

    f32x4 hacc[2][2][2];                              // [batch][mt][nt] = H^T
    {
        bhalf8 wf[2];
        #pragma unroll
        for (int nt = 0; nt < 2; ++nt) {              // Wa-path init (K=8)
            wf[nt] = zf8;
            if (k8) {
                const float* p = wa + (nt*16 + lr) * 8;
                #pragma unroll
                for (int i = 0; i < 8; ++i) wf[nt][i] = f2bf(p[i]);
            }
        }
        #pragma unroll
        for (int b = 0; b < 2; ++b)
        #pragma unroll
        for (int mt = 0; mt < 2; ++mt)
        #pragma unroll
        for (int nt = 0; nt < 2; ++nt)
            hacc[b][mt][nt] = MFMA(wf[nt], atf[b][mt], zf4);
    }

    const int i0 = rowbase + lr;                      // mt=0 row
    const int i1 = rowbase + 16 + lr;                 // mt=1 row

    for (int cc = 0; cc < 8; ++cc) {                  // 8 chunks of 32 att-cols
        // Wca fragments for this chunk (L2; shared by both batches)
        bhalf8 bwc[2];
        #pragma unroll
        for (int nt = 0; nt < 2; ++nt)
            bwc[nt] = *(const bhalf8*)(wca + (nt*16 + lr)*256 + cc*32 + lg*8);

        f32x4 mT[2][2][2];                            // [batch][mt][nt] z^T frags
        #pragma unroll
        for (int nt = 0; nt < 2; ++nt) {
            bhalf8 gf0 = k8 ? *(const bhalf8*)(sG + ((0*2+mod)*256 + cc*32 + nt*16 + lr)*8) : zf8;
            bhalf8 gf1 = k8 ? *(const bhalf8*)(sG + ((1*2+mod)*256 + cc*32 + nt*16 + lr)*8) : zf8;
            #pragma unroll
            for (int mt = 0; mt < 2; ++mt) {
                mT[0][mt][nt] = MFMA(gf0, atf[0][mt], zf4);
                mT[1][mt][nt] = MFMA(gf1, atf[1][mt], zf4);
            }
        }
        // batch-sequential z round-trip on the shared stripe
        #pragma unroll
        for (int b = 0; b < 2; ++b) {
            WFENCE();   // prior z reads of this stripe complete before overwrite
            #pragma unroll
            for (int mt = 0; mt < 2; ++mt) {
                int ir = mt ? i1 : i0;
                #pragma unroll
                for (int nt = 0; nt < 2; ++nt) {
                    float v[4];
                    #pragma unroll
                    for (int r = 0; r < 4; ++r) {
                        float e = fexp2(mT[b][mt][nt][r]);          // prefolded
                        v[r] = fmaf(-2.0f, frcp(e + 1.0f), 1.0f);   // tanh
                    }
                    uint2v u;
                    u[0] = pk2bf(v[0], v[1]);
                    u[1] = pk2bf(v[2], v[3]);
                    *(uint2v*)(zs + ir*ZPITCH + nt*32 + lg*8) = u;
                }
            }
            WFENCE();   // z writes visible (wave-local) before reads
            bhalf8 az0 = *(const bhalf8*)(zs + i0*ZPITCH + lg*16);
            bhalf8 az1 = *(const bhalf8*)(zs + i1*ZPITCH + lg*16);
            #pragma unroll
            for (int nt = 0; nt < 2; ++nt) {
                hacc[b][0][nt] = MFMA(bwc[nt], az0, hacc[b][0][nt]);
                hacc[b][1][nt] = MFMA(bwc[nt], az1, hacc[b][1][nt]);
            }
        }
    }

    // H epilogue: batch-sequential on the same stripe
    bhalf8 whaf = zf8;                    // Wha B-frag (8 real cols, K=32 full)
    if (lr < 8) {
        const float* p = wha + lr*32 + lg*8;
        #pragma unroll
        for (int i = 0; i < 8; ++i) whaf[i] = f2bf(p[i]);
    }
    f4v wcf[2];
    #pragma unroll
    for (int mt = 0; mt < 2; ++mt)
        wcf[mt] = *(const f4v*)(wcomb + mod*128 + rowbase + mt*16 + lg*4);

    #pragma unroll
    for (int b = 0; b < 2; ++b) {
        WFENCE();       // prior stripe reads done before H overlay writes
        #pragma unroll
        for (int mt = 0; mt < 2; ++mt) {
            int ir = mt ? i1 : i0;
            #pragma unroll
            for (int nt = 0; nt < 2; ++nt) {
                uint2v u;
                u[0] = pk2bf(fmaxf(hacc[b][mt][nt][0], 0.f),
                             fmaxf(hacc[b][mt][nt][1], 0.f));
                u[1] = pk2bf(fmaxf(hacc[b][mt][nt][2], 0.f),
                             fmaxf(hacc[b][mt][nt][3], 0.f));
                *(uint2v*)(zs + ir*ZPITCH + nt*32 + lg*8) = u;
            }
        }
        WFENCE();
        #pragma unroll
        for (int mt = 0; mt < 2; ++mt) {
            int ir = mt ? i1 : i0;
            bhalf8 af = *(const bhalf8*)(zs + ir*ZPITCH + lg*16);
            f32x4 oa = MFMA(af, whaf, zf4);           // D[i-local][t'=lr]
            if (lr < 8) {
                #pragma unroll
                for (int r = 0; r < 4; ++r) {
                    int irow = rowbase + mt*16 + lg*4 + r;
                    float val = oa[r] + bf2f(s_At[b][mod][irow][lr]);
                    pacc[b] += val * wcf[mt][r];
                }
            }
        }
    }

    // reduce over lg (xor 16/32), then over 8 waves
    #pragma unroll
    for (int b = 0; b < 2; ++b) {
        pacc[b] += __shfl_xor(pacc[b], 16, 64);
        pacc[b] += __shfl_xor(pacc[b], 32, 64);
    }
    if (l < 8) { s_red[w][0][l] = pacc[0]; s_red[w][1][l] = pacc[1]; }
    __syncthreads();
    if (tid < 16) {
        int b = tid >> 3, t = tid & 7;
        float s = *(const float*)(ws + OFF_BC);
        #pragma unroll
        for (int q = 0; q < 8; ++q) s += s_red[q][b][t];
        out[((long)blockIdx.x * 2 + b) * 8 + t] = s;
    }
}

extern "C" void kernel_launch(void* const* d_in, const int* in_sizes, int n_in,
                              void* d_out, int out_size, void* d_ws, size_t ws_size,
                              hipStream_t stream)
{
    const float* f1    = (const float*)d_in[0];
    const float* f2    = (const float*)d_in[1];
    const float* We1   = (const float*)d_in[2];
    const float* be1   = (const float*)d_in[3];
    const float* We2   = (const float*)d_in[4];
    const float* be2   = (const float*)d_in[5];
    const float* Waffa = (const float*)d_in[6];
    const float* Waffv = (const float*)d_in[7];
    const float* Wa    = (const float*)d_in[8];
    const float* Wv    = (const float*)d_in[9];
    const float* Wca   = (const float*)d_in[10];
    const float* Wcv   = (const float*)d_in[11];
    const float* Wha   = (const float*)d_in[12];
    const float* Whv   = (const float*)d_in[13];
    const float* Wr1   = (const float*)d_in[14];
    const float* br1   = (const float*)d_in[15];
    const float* Wr2   = (const float*)d_in[16];
    const float* br2   = (const float*)d_in[17];
    char* ws = (char*)d_ws;
    float* out = (float*)d_out;

    k_prep <<<256,  256, 0, stream>>>(We1, We2, Wca, Wcv, Wr1, br1, Wr2, br2, ws);
    k_fused<<<2048, 512, 0, stream>>>(f1, f2, be1, be2, Waffa, Waffv,
                                      Wa, Wv, Wha, Whv, ws, out);
}

// Round 15
// 143.952 us; speedup vs baseline: 1.5959x; 1.5959x over previous
//
#include <hip/hip_runtime.h>
#include <hip/hip_bf16.h>

#define DEV __device__ __forceinline__

typedef __attribute__((ext_vector_type(8))) short bhalf8;   // 8 bf16 (4 VGPR)
typedef __attribute__((ext_vector_type(4))) float f32x4;    // MFMA C/D
typedef __attribute__((ext_vector_type(4))) float f4v;
typedef __attribute__((ext_vector_type(4))) unsigned uint4v;
typedef __attribute__((ext_vector_type(2))) unsigned uint2v;

// ---- workspace layout (bytes) ----
constexpr size_t OFF_WE1   = 0;         // [128][512] bf16
constexpr size_t OFF_WE2   = 131072;
constexpr size_t OFF_WCA   = 262144;    // [32][256] bf16
constexpr size_t OFF_WCV   = 278528;
constexpr size_t OFF_WCOMB = 294912;    // [256] f32 = W_r2 @ W_r1
constexpr size_t OFF_BC    = 295936;    // scalar f32 = b_r1.W_r2 + b_r2

DEV short f2bf(float f) {               // RNE float->bf16 bits
    __hip_bfloat16 h = __float2bfloat16(f);
    return __builtin_bit_cast(short, h);
}
DEV float bf2f(short s) {
    unsigned u = ((unsigned)(unsigned short)s) << 16;
    return __builtin_bit_cast(float, u);
}
DEV unsigned pk2bf(float lo, float hi) {  // word = bits(hi)<<16 | bits(lo)
    unsigned ul = (unsigned)(unsigned short)f2bf(lo);
    unsigned uh = (unsigned)(unsigned short)f2bf(hi);
    return (uh << 16) | ul;
}
DEV float fexp2(float x) { float r; asm("v_exp_f32 %0, %1" : "=v"(r) : "v"(x)); return r; }
DEV float frcp (float x) { float r; asm("v_rcp_f32 %0, %1" : "=v"(r) : "v"(x)); return r; }

#define WFENCE() asm volatile("s_waitcnt lgkmcnt(0)" ::: "memory")
#define MFMA(a,b,c) __builtin_amdgcn_mfma_f32_16x16x32_bf16(a,b,c,0,0,0)

// z/H tile row pitch: 80 B (20-bank step) -> <=2-way bank aliasing (free).
// z stripes are PER-MOD only (batch-sequential round-trip) -> LDS 46080 B
// -> 3 blocks/CU. R14 lesson: launch_bounds (512,6) capped VGPR at ~85 and
// SPILLED (WRITE_SIZE 132 MB, dur +70%); (512,4) gives budget 128, usage ~60.
constexpr int ZPITCH = 80;
constexpr int ZSTRIPE = 128 * ZPITCH;   // per mod stripe: 10240 B
constexpr int ZBASE  = 16384;           // z region after G region

// ---------------- prep: bf16 weights + collapsed regressor ----------------
__global__ void k_prep(const float* __restrict__ We1, const float* __restrict__ We2,
                       const float* __restrict__ Wca, const float* __restrict__ Wcv,
                       const float* __restrict__ Wr1, const float* __restrict__ br1,
                       const float* __restrict__ Wr2, const float* __restrict__ br2,
                       char* __restrict__ ws)
{
    int idx = blockIdx.x * 256 + threadIdx.x;      // 65536 threads
    short* we1 = (short*)(ws + OFF_WE1);
    short* we2 = (short*)(ws + OFF_WE2);
    short* wca = (short*)(ws + OFF_WCA);
    short* wcv = (short*)(ws + OFF_WCV);
    float* wcomb = (float*)(ws + OFF_WCOMB);
    float* bcp   = (float*)(ws + OFF_BC);

    we1[idx] = f2bf(We1[idx]);
    we2[idx] = f2bf(We2[idx]);
    if (idx < 8192) { wca[idx] = f2bf(Wca[idx]); wcv[idx] = f2bf(Wcv[idx]); }
    if (idx < 256) {                    // wcomb[j] = sum_q Wr2[q]*Wr1[q][j]
        float s = 0.0f;
        for (int q = 0; q < 128; ++q) s += Wr2[q] * Wr1[q * 256 + idx];
        wcomb[idx] = s;
    }
    if (idx == 0) {                     // bc = br1 . Wr2 + br2
        float s = br2[0];
        for (int q = 0; q < 128; ++q) s += br1[q] * Wr2[q];
        bcp[0] = s;
    }
}

// -------- fully fused, 2 batches/block: encoder + co-attn + regressor --------
// 512 threads (8 waves). E1: wave -> (mod = w>>2, 32 cols, both batches).
// M/H: wave -> (mod = w>>2, rows (w&3)*32..+31); mT MFMAs batch-interleaved,
// z LDS round-trip batch-SEQUENTIAL on a shared per-mod stripe (halves LDS).
__global__ __launch_bounds__(512, 4) void k_fused(
    const float* __restrict__ f1,   const float* __restrict__ f2,
    const float* __restrict__ be1,  const float* __restrict__ be2,
    const float* __restrict__ waffa,const float* __restrict__ waffv,
    const float* __restrict__ Wa,   const float* __restrict__ Wv,
    const float* __restrict__ Wha,  const float* __restrict__ Whv,
    const char* __restrict__ ws, float* __restrict__ out)
{
    // [0,16K): G (after E1); during E0/E1 the f-stage overlay uses [0,32K)
    // [16K, 16K+2*10240): z/H stripes per mod (shared by both batches)
    __shared__ __align__(16) char  s_z[ZBASE + 2 * ZSTRIPE];   // 36864 B
    __shared__ __align__(16) short s_At[2][2][128][8];// [batch][mod] av bf16 [i][t]
    __shared__ float s_waff[2][8][8];
    __shared__ float s_red[8][2][8];

    short* sG = (short*)s_z;                          // [b*2+m][256][8] after E1

    const int tid = threadIdx.x;
    const int w = tid >> 6, l = tid & 63, lr = l & 15, lg = l >> 4;
    const int mod = w >> 2;              // wave's modality
    const int wn  = w & 3;               // wave index within modality group
    const bool k8 = (lg == 0);           // lanes carrying the real K=8 slice

    const short* we   = (const short*)(ws + (mod ? OFF_WE2 : OFF_WE1));
    const short* wca  = (const short*)(ws + (mod ? OFF_WCV : OFF_WCA));
    const float* wcomb= (const float*)(ws + OFF_WCOMB);
    const float* be   = mod ? be2 : be1;
    const float* wha  = mod ? Whv : Wha;
    const float* wa   = mod ? Wv  : Wa;

    const bhalf8 zf8 = {0,0,0,0,0,0,0,0};
    const f32x4  zf4 = {0.f,0.f,0.f,0.f};

    // ---- E0: stage f rows (2 batches x 2 mods) bf16 into s_z, 8KB stripes ----
    {
        int row = tid >> 6, k0 = (tid & 63) * 8;
        #pragma unroll
        for (int b = 0; b < 2; ++b)
        #pragma unroll
        for (int m = 0; m < 2; ++m) {
            const float* fp = (m ? f2 : f1)
                + ((long)blockIdx.x * 2 + b) * 4096 + row * 512 + k0;
            f4v a0 = *(const f4v*)fp;
            f4v a1 = *(const f4v*)(fp + 4);
            uint4v u;
            u[0] = pk2bf(a0[0], a0[1]); u[1] = pk2bf(a0[2], a0[3]);
            u[2] = pk2bf(a1[0], a1[1]); u[3] = pk2bf(a1[2], a1[3]);
            int off = ((b*2+m) * 8192 + row * 1024 + k0 * 2) ^ (row << 4);
            *(uint4v*)(s_z + off) = u;
        }
        if (tid < 128) {
            const float* src = (tid < 64) ? waffa : waffv;
            s_waff[tid >> 6][(tid >> 3) & 7][tid & 7] = src[tid & 63];
        }
    }
    __syncthreads();

    // ---- E1: encoder GEMM, both batches share each We fragment ----
    {
        f32x4 acc[2][2] = {{zf4, zf4}, {zf4, zf4}};   // [batch][nt]
        const int r8 = lr & 7;
        const int fs0 = (0*2 + mod) * 8192 + r8 * 1024;
        const int fs1 = (1*2 + mod) * 8192 + r8 * 1024;
        const int fswz = r8 << 4;
        const short* wp0 = we + (wn*32 + lr) * 512 + lg * 8;
        const short* wp1 = wp0 + 16 * 512;
        bhalf8 bw0 = *(const bhalf8*)wp0;             // prefetched fragment
        bhalf8 bw1 = *(const bhalf8*)wp1;
        #pragma unroll
        for (int ks = 0; ks < 16; ++ks) {
            int fo = (ks*64 + lg*16) ^ fswz;
            bhalf8 af0 = *(const bhalf8*)(s_z + fs0 + fo);
            bhalf8 af1 = *(const bhalf8*)(s_z + fs1 + fo);
            bhalf8 nb0 = bw0, nb1 = bw1;
            if (ks < 15) {                            // software prefetch ks+1
                nb0 = *(const bhalf8*)(wp0 + (ks+1) * 32);
                nb1 = *(const bhalf8*)(wp1 + (ks+1) * 32);
            }
            acc[0][0] = MFMA(af0, bw0, acc[0][0]);
            acc[0][1] = MFMA(af0, bw1, acc[0][1]);
            acc[1][0] = MFMA(af1, bw0, acc[1][0]);
            acc[1][1] = MFMA(af1, bw1, acc[1][1]);
            bw0 = nb0; bw1 = nb1;
        }
        if (lg < 2) {                                 // t = lg*4+r in 0..7
            #pragma unroll
            for (int b = 0; b < 2; ++b)
            #pragma unroll
            for (int nt = 0; nt < 2; ++nt) {
                int n = wn*32 + nt*16 + lr;
                float bias = be[n];
                uint2v u;
                u[0] = pk2bf(acc[b][nt][0]+bias, acc[b][nt][1]+bias);
                u[1] = pk2bf(acc[b][nt][2]+bias, acc[b][nt][3]+bias);
                *(uint2v*)&s_At[b][mod][n][lg*4] = u;
            }
        }
    }
    __syncthreads();   // f-stage dead; G + z regions become writable

    // ---- G: G' = (Waff @ av) * (scale*2*log2e)  [tanh prefold] ----
    {
        const float kfold = (1.0f / 16.0f) * 2.0f * 1.44269504088896340736f;
        #pragma unroll
        for (int u = 0; u < 2; ++u) {
            int idx = tid + 512 * u;                  // 0..1023
            int b = idx >> 9, m = (idx >> 8) & 1, j = idx & 255;
            const short* avp = (j < 128) ? &s_At[b][0][j][0]
                                         : &s_At[b][1][j - 128][0];
            bhalf8 avv = *(const bhalf8*)avp;
            float avf[8];
            #pragma unroll
            for (int t = 0; t < 8; ++t) avf[t] = bf2f(avv[t]);
            float g[8] = {0,0,0,0,0,0,0,0};
            #pragma unroll
            for (int t = 0; t < 8; ++t)
                #pragma unroll
                for (int p = 0; p < 8; ++p) g[p] += s_waff[m][p][t] * avf[t];
            bhalf8 gv;
            #pragma unroll
            for (int p = 0; p < 8; ++p) gv[p] = f2bf(g[p] * kfold);
            *(bhalf8*)(sG + ((b*2+m)*256 + j)*8) = gv;
        }
    }
    __syncthreads();

    // ---- M/H: wave owns (mod, rows rowbase..+31); shared per-mod z stripe ----
    const int rowbase = wn * 32;
    char* zs = s_z + ZBASE + mod * ZSTRIPE;           // shared stripe (both b)
    float pacc[2] = {0.0f, 0.0f};

    bhalf8 atf[2][2];                                 // [batch][mt]
    #pragma unroll
    for (int b = 0; b < 2; ++b)
    #pragma unroll
    for (int mt = 0; mt < 2; ++mt)
        atf[b][mt] = k8 ? *(const bhalf8*)&s_At[b][mod][rowbase + mt*16 + lr][0]
                        : zf8;

    f32x4 hacc[2][2][2];                              // [batch][mt][nt] = H^T
    {
        bhalf8 wf[2];
        #pragma unroll
        for (int nt = 0; nt < 2; ++nt) {              // Wa-path init (K=8)
            wf[nt] = zf8;
            if (k8) {
                const float* p = wa + (nt*16 + lr) * 8;
                #pragma unroll
                for (int i = 0; i < 8; ++i) wf[nt][i] = f2bf(p[i]);
            }
        }
        #pragma unroll
        for (int b = 0; b < 2; ++b)
        #pragma unroll
        for (int mt = 0; mt < 2; ++mt)
        #pragma unroll
        for (int nt = 0; nt < 2; ++nt)
            hacc[b][mt][nt] = MFMA(wf[nt], atf[b][mt], zf4);
    }

    const int i0 = rowbase + lr;                      // mt=0 row
    const int i1 = rowbase + 16 + lr;                 // mt=1 row

    for (int cc = 0; cc < 8; ++cc) {                  // 8 chunks of 32 att-cols
        // Wca fragments for this chunk (L2; shared by both batches)
        bhalf8 bwc[2];
        #pragma unroll
        for (int nt = 0; nt < 2; ++nt)
            bwc[nt] = *(const bhalf8*)(wca + (nt*16 + lr)*256 + cc*32 + lg*8);

        f32x4 mT[2][2][2];                            // [batch][mt][nt] z^T frags
        #pragma unroll
        for (int nt = 0; nt < 2; ++nt) {
            bhalf8 gf0 = k8 ? *(const bhalf8*)(sG + ((0*2+mod)*256 + cc*32 + nt*16 + lr)*8) : zf8;
            bhalf8 gf1 = k8 ? *(const bhalf8*)(sG + ((1*2+mod)*256 + cc*32 + nt*16 + lr)*8) : zf8;
            #pragma unroll
            for (int mt = 0; mt < 2; ++mt) {
                mT[0][mt][nt] = MFMA(gf0, atf[0][mt], zf4);
                mT[1][mt][nt] = MFMA(gf1, atf[1][mt], zf4);
            }
        }
        // batch-sequential z round-trip on the shared stripe
        #pragma unroll
        for (int b = 0; b < 2; ++b) {
            WFENCE();   // prior z reads of this stripe complete before overwrite
            #pragma unroll
            for (int mt = 0; mt < 2; ++mt) {
                int ir = mt ? i1 : i0;
                #pragma unroll
                for (int nt = 0; nt < 2; ++nt) {
                    float v[4];
                    #pragma unroll
                    for (int r = 0; r < 4; ++r) {
                        float e = fexp2(mT[b][mt][nt][r]);          // prefolded
                        v[r] = fmaf(-2.0f, frcp(e + 1.0f), 1.0f);   // tanh
                    }
                    uint2v u;
                    u[0] = pk2bf(v[0], v[1]);
                    u[1] = pk2bf(v[2], v[3]);
                    *(uint2v*)(zs + ir*ZPITCH + nt*32 + lg*8) = u;
                }
            }
            WFENCE();   // z writes visible (wave-local) before reads
            bhalf8 az0 = *(const bhalf8*)(zs + i0*ZPITCH + lg*16);
            bhalf8 az1 = *(const bhalf8*)(zs + i1*ZPITCH + lg*16);
            #pragma unroll
            for (int nt = 0; nt < 2; ++nt) {
                hacc[b][0][nt] = MFMA(bwc[nt], az0, hacc[b][0][nt]);
                hacc[b][1][nt] = MFMA(bwc[nt], az1, hacc[b][1][nt]);
            }
        }
    }

    // H epilogue: batch-sequential on the same stripe
    bhalf8 whaf = zf8;                    // Wha B-frag (8 real cols, K=32 full)
    if (lr < 8) {
        const float* p = wha + lr*32 + lg*8;
        #pragma unroll
        for (int i = 0; i < 8; ++i) whaf[i] = f2bf(p[i]);
    }
    f4v wcf[2];
    #pragma unroll
    for (int mt = 0; mt < 2; ++mt)
        wcf[mt] = *(const f4v*)(wcomb + mod*128 + rowbase + mt*16 + lg*4);

    #pragma unroll
    for (int b = 0; b < 2; ++b) {
        WFENCE();       // prior stripe reads done before H overlay writes
        #pragma unroll
        for (int mt = 0; mt < 2; ++mt) {
            int ir = mt ? i1 : i0;
            #pragma unroll
            for (int nt = 0; nt < 2; ++nt) {
                uint2v u;
                u[0] = pk2bf(fmaxf(hacc[b][mt][nt][0], 0.f),
                             fmaxf(hacc[b][mt][nt][1], 0.f));
                u[1] = pk2bf(fmaxf(hacc[b][mt][nt][2], 0.f),
                             fmaxf(hacc[b][mt][nt][3], 0.f));
                *(uint2v*)(zs + ir*ZPITCH + nt*32 + lg*8) = u;
            }
        }
        WFENCE();
        #pragma unroll
        for (int mt = 0; mt < 2; ++mt) {
            int ir = mt ? i1 : i0;
            bhalf8 af = *(const bhalf8*)(zs + ir*ZPITCH + lg*16);
            f32x4 oa = MFMA(af, whaf, zf4);           // D[i-local][t'=lr]
            if (lr < 8) {
                #pragma unroll
                for (int r = 0; r < 4; ++r) {
                    int irow = rowbase + mt*16 + lg*4 + r;
                    float val = oa[r] + bf2f(s_At[b][mod][irow][lr]);
                    pacc[b] += val * wcf[mt][r];
                }
            }
        }
    }

    // reduce over lg (xor 16/32), then over 8 waves
    #pragma unroll
    for (int b = 0; b < 2; ++b) {
        pacc[b] += __shfl_xor(pacc[b], 16, 64);
        pacc[b] += __shfl_xor(pacc[b], 32, 64);
    }
    if (l < 8) { s_red[w][0][l] = pacc[0]; s_red[w][1][l] = pacc[1]; }
    __syncthreads();
    if (tid < 16) {
        int b = tid >> 3, t = tid & 7;
        float s = *(const float*)(ws + OFF_BC);
        #pragma unroll
        for (int q = 0; q < 8; ++q) s += s_red[q][b][t];
        out[((long)blockIdx.x * 2 + b) * 8 + t] = s;
    }
}

extern "C" void kernel_launch(void* const* d_in, const int* in_sizes, int n_in,
                              void* d_out, int out_size, void* d_ws, size_t ws_size,
                              hipStream_t stream)
{
    const float* f1    = (const float*)d_in[0];
    const float* f2    = (const float*)d_in[1];
    const float* We1   = (const float*)d_in[2];
    const float* be1   = (const float*)d_in[3];
    const float* We2   = (const float*)d_in[4];
    const float* be2   = (const float*)d_in[5];
    const float* Waffa = (const float*)d_in[6];
    const float* Waffv = (const float*)d_in[7];
    const float* Wa    = (const float*)d_in[8];
    const float* Wv    = (const float*)d_in[9];
    const float* Wca   = (const float*)d_in[10];
    const float* Wcv   = (const float*)d_in[11];
    const float* Wha   = (const float*)d_in[12];
    const float* Whv   = (const float*)d_in[13];
    const float* Wr1   = (const float*)d_in[14];
    const float* br1   = (const float*)d_in[15];
    const float* Wr2   = (const float*)d_in[16];
    const float* br2   = (const float*)d_in[17];
    char* ws = (char*)d_ws;
    float* out = (float*)d_out;

    k_prep <<<256,  256, 0, stream>>>(We1, We2, Wca, Wcv, Wr1, br1, Wr2, br2, ws);
    k_fused<<<2048, 512, 0, stream>>>(f1, f2, be1, be2, Waffa, Waffv,
                                      Wa, Wv, Wha, Whv, ws, out);
}

// Round 16
// 137.873 us; speedup vs baseline: 1.6663x; 1.0441x over previous
//
#include <hip/hip_runtime.h>
#include <hip/hip_bf16.h>

#define DEV __device__ __forceinline__

typedef __attribute__((ext_vector_type(8))) short bhalf8;   // 8 bf16 (4 VGPR)
typedef __attribute__((ext_vector_type(4))) float f32x4;    // MFMA C/D
typedef __attribute__((ext_vector_type(4))) float f4v;
typedef __attribute__((ext_vector_type(4))) unsigned uint4v;
typedef __attribute__((ext_vector_type(2))) unsigned uint2v;

// ---- workspace layout (bytes) ----
constexpr size_t OFF_WE1   = 0;         // [128][512] bf16
constexpr size_t OFF_WE2   = 131072;
constexpr size_t OFF_WCA   = 262144;    // [32][256] bf16
constexpr size_t OFF_WCV   = 278528;
constexpr size_t OFF_WCOMB = 294912;    // [256] f32 = W_r2 @ W_r1
constexpr size_t OFF_BC    = 295936;    // scalar f32 = b_r1.W_r2 + b_r2

DEV short f2bf(float f) {               // RNE float->bf16 bits (scalar, cold paths)
    __hip_bfloat16 h = __float2bfloat16(f);
    return __builtin_bit_cast(short, h);
}
DEV float bf2f(short s) {
    unsigned u = ((unsigned)(unsigned short)s) << 16;
    return __builtin_bit_cast(float, u);
}
// HOT path: HW packed f32->bf16 (1 inst for 2 conversions). hipcc's
// __float2bfloat16 emits a ~6-inst RNE software sequence; R15 counters showed
// ~5900 VALU inst/wave (3.7x hand count) -- pk2bf was the hidden VALU hog.
DEV unsigned pk2bf(float lo, float hi) {  // word = bits(hi)<<16 | bits(lo)
    unsigned r;
    asm("v_cvt_pk_bf16_f32 %0, %1, %2" : "=v"(r) : "v"(lo), "v"(hi));
    return r;
}
DEV float fexp2(float x) { float r; asm("v_exp_f32 %0, %1" : "=v"(r) : "v"(x)); return r; }
DEV float frcp (float x) { float r; asm("v_rcp_f32 %0, %1" : "=v"(r) : "v"(x)); return r; }

#define WFENCE() asm volatile("s_waitcnt lgkmcnt(0)" ::: "memory")
#define MFMA(a,b,c) __builtin_amdgcn_mfma_f32_16x16x32_bf16(a,b,c,0,0,0)

// z/H tile row pitch: 80 B (20-bank step) -> <=2-way bank aliasing (free).
// z stripes are PER-MOD only (batch-sequential round-trip) -> LDS 46080 B.
// Registers (VGPR+AGPR ~100/wave, unified file) cap us at 2 blocks/CU; the
// occupancy lever is closed (R14: forcing 85 regs spilled 132 MB).
constexpr int ZPITCH = 80;
constexpr int ZSTRIPE = 128 * ZPITCH;   // per mod stripe: 10240 B
constexpr int ZBASE  = 16384;           // z region after G region

// ---------------- prep: bf16 weights + collapsed regressor ----------------
__global__ void k_prep(const float* __restrict__ We1, const float* __restrict__ We2,
                       const float* __restrict__ Wca, const float* __restrict__ Wcv,
                       const float* __restrict__ Wr1, const float* __restrict__ br1,
                       const float* __restrict__ Wr2, const float* __restrict__ br2,
                       char* __restrict__ ws)
{
    int idx = blockIdx.x * 256 + threadIdx.x;      // 65536 threads
    short* we1 = (short*)(ws + OFF_WE1);
    short* we2 = (short*)(ws + OFF_WE2);
    short* wca = (short*)(ws + OFF_WCA);
    short* wcv = (short*)(ws + OFF_WCV);
    float* wcomb = (float*)(ws + OFF_WCOMB);
    float* bcp   = (float*)(ws + OFF_BC);

    we1[idx] = f2bf(We1[idx]);
    we2[idx] = f2bf(We2[idx]);
    if (idx < 8192) { wca[idx] = f2bf(Wca[idx]); wcv[idx] = f2bf(Wcv[idx]); }
    if (idx < 256) {                    // wcomb[j] = sum_q Wr2[q]*Wr1[q][j]
        float s = 0.0f;
        for (int q = 0; q < 128; ++q) s += Wr2[q] * Wr1[q * 256 + idx];
        wcomb[idx] = s;
    }
    if (idx == 0) {                     // bc = br1 . Wr2 + br2
        float s = br2[0];
        for (int q = 0; q < 128; ++q) s += br1[q] * Wr2[q];
        bcp[0] = s;
    }
}

// -------- fully fused, 2 batches/block: encoder + co-attn + regressor --------
// 512 threads (8 waves). E1: wave -> (mod = w>>2, 32 cols, both batches).
// M/H: wave -> (mod = w>>2, rows (w&3)*32..+31); mT MFMAs batch-interleaved,
// z LDS round-trip batch-SEQUENTIAL on a shared per-mod stripe.
__global__ __launch_bounds__(512, 4) void k_fused(
    const float* __restrict__ f1,   const float* __restrict__ f2,
    const float* __restrict__ be1,  const float* __restrict__ be2,
    const float* __restrict__ waffa,const float* __restrict__ waffv,
    const float* __restrict__ Wa,   const float* __restrict__ Wv,
    const float* __restrict__ Wha,  const float* __restrict__ Whv,
    const char* __restrict__ ws, float* __restrict__ out)
{
    // [0,16K): G (after E1); during E0/E1 the f-stage overlay uses [0,32K)
    // [16K, 16K+2*10240): z/H stripes per mod (shared by both batches)
    __shared__ __align__(16) char  s_z[ZBASE + 2 * ZSTRIPE];   // 36864 B
    __shared__ __align__(16) short s_At[2][2][128][8];// [batch][mod] av bf16 [i][t]
    __shared__ float s_waff[2][8][8];
    __shared__ float s_red[8][2][8];

    short* sG = (short*)s_z;                          // [b*2+m][256][8] after E1

    const int tid = threadIdx.x;
    const int w = tid >> 6, l = tid & 63, lr = l & 15, lg = l >> 4;
    const int mod = w >> 2;              // wave's modality
    const int wn  = w & 3;               // wave index within modality group
    const bool k8 = (lg == 0);           // lanes carrying the real K=8 slice

    const short* we   = (const short*)(ws + (mod ? OFF_WE2 : OFF_WE1));
    const short* wca  = (const short*)(ws + (mod ? OFF_WCV : OFF_WCA));
    const float* wcomb= (const float*)(ws + OFF_WCOMB);
    const float* be   = mod ? be2 : be1;
    const float* wha  = mod ? Whv : Wha;
    const float* wa   = mod ? Wv  : Wa;

    const bhalf8 zf8 = {0,0,0,0,0,0,0,0};
    const f32x4  zf4 = {0.f,0.f,0.f,0.f};

    // ---- E0: stage f rows (2 batches x 2 mods) bf16 into s_z, 8KB stripes ----
    {
        int row = tid >> 6, k0 = (tid & 63) * 8;
        #pragma unroll
        for (int b = 0; b < 2; ++b)
        #pragma unroll
        for (int m = 0; m < 2; ++m) {
            const float* fp = (m ? f2 : f1)
                + ((long)blockIdx.x * 2 + b) * 4096 + row * 512 + k0;
            f4v a0 = *(const f4v*)fp;
            f4v a1 = *(const f4v*)(fp + 4);
            uint4v u;
            u[0] = pk2bf(a0[0], a0[1]); u[1] = pk2bf(a0[2], a0[3]);
            u[2] = pk2bf(a1[0], a1[1]); u[3] = pk2bf(a1[2], a1[3]);
            int off = ((b*2+m) * 8192 + row * 1024 + k0 * 2) ^ (row << 4);
            *(uint4v*)(s_z + off) = u;
        }
        if (tid < 128) {
            const float* src = (tid < 64) ? waffa : waffv;
            s_waff[tid >> 6][(tid >> 3) & 7][tid & 7] = src[tid & 63];
        }
    }
    __syncthreads();

    // ---- E1: encoder GEMM, both batches share each We fragment ----
    {
        f32x4 acc[2][2] = {{zf4, zf4}, {zf4, zf4}};   // [batch][nt]
        const int r8 = lr & 7;
        const int fs0 = (0*2 + mod) * 8192 + r8 * 1024;
        const int fs1 = (1*2 + mod) * 8192 + r8 * 1024;
        const int fswz = r8 << 4;
        const short* wp0 = we + (wn*32 + lr) * 512 + lg * 8;
        const short* wp1 = wp0 + 16 * 512;
        bhalf8 bw0 = *(const bhalf8*)wp0;             // prefetched fragment
        bhalf8 bw1 = *(const bhalf8*)wp1;
        #pragma unroll
        for (int ks = 0; ks < 16; ++ks) {
            int fo = (ks*64 + lg*16) ^ fswz;
            bhalf8 af0 = *(const bhalf8*)(s_z + fs0 + fo);
            bhalf8 af1 = *(const bhalf8*)(s_z + fs1 + fo);
            bhalf8 nb0 = bw0, nb1 = bw1;
            if (ks < 15) {                            // software prefetch ks+1
                nb0 = *(const bhalf8*)(wp0 + (ks+1) * 32);
                nb1 = *(const bhalf8*)(wp1 + (ks+1) * 32);
            }
            acc[0][0] = MFMA(af0, bw0, acc[0][0]);
            acc[0][1] = MFMA(af0, bw1, acc[0][1]);
            acc[1][0] = MFMA(af1, bw0, acc[1][0]);
            acc[1][1] = MFMA(af1, bw1, acc[1][1]);
            bw0 = nb0; bw1 = nb1;
        }
        if (lg < 2) {                                 // t = lg*4+r in 0..7
            #pragma unroll
            for (int b = 0; b < 2; ++b)
            #pragma unroll
            for (int nt = 0; nt < 2; ++nt) {
                int n = wn*32 + nt*16 + lr;
                float bias = be[n];
                uint2v u;
                u[0] = pk2bf(acc[b][nt][0]+bias, acc[b][nt][1]+bias);
                u[1] = pk2bf(acc[b][nt][2]+bias, acc[b][nt][3]+bias);
                *(uint2v*)&s_At[b][mod][n][lg*4] = u;
            }
        }
    }
    __syncthreads();   // f-stage dead; G + z regions become writable

    // ---- G: G' = (Waff @ av) * (scale*2*log2e)  [tanh prefold] ----
    {
        const float kfold = (1.0f / 16.0f) * 2.0f * 1.44269504088896340736f;
        #pragma unroll
        for (int u = 0; u < 2; ++u) {
            int idx = tid + 512 * u;                  // 0..1023
            int b = idx >> 9, m = (idx >> 8) & 1, j = idx & 255;
            const short* avp = (j < 128) ? &s_At[b][0][j][0]
                                         : &s_At[b][1][j - 128][0];
            bhalf8 avv = *(const bhalf8*)avp;
            float avf[8];
            #pragma unroll
            for (int t = 0; t < 8; ++t) avf[t] = bf2f(avv[t]);
            float g[8] = {0,0,0,0,0,0,0,0};
            #pragma unroll
            for (int t = 0; t < 8; ++t)
                #pragma unroll
                for (int p = 0; p < 8; ++p) g[p] += s_waff[m][p][t] * avf[t];
            uint4v gv;
            gv[0] = pk2bf(g[0]*kfold, g[1]*kfold);
            gv[1] = pk2bf(g[2]*kfold, g[3]*kfold);
            gv[2] = pk2bf(g[4]*kfold, g[5]*kfold);
            gv[3] = pk2bf(g[6]*kfold, g[7]*kfold);
            *(uint4v*)(sG + ((b*2+m)*256 + j)*8) = gv;
        }
    }
    __syncthreads();

    // ---- M/H: wave owns (mod, rows rowbase..+31); shared per-mod z stripe ----
    const int rowbase = wn * 32;
    char* zs = s_z + ZBASE + mod * ZSTRIPE;           // shared stripe (both b)
    float pacc[2] = {0.0f, 0.0f};

    bhalf8 atf[2][2];                                 // [batch][mt]
    #pragma unroll
    for (int b = 0; b < 2; ++b)
    #pragma unroll
    for (int mt = 0; mt < 2; ++mt)
        atf[b][mt] = k8 ? *(const bhalf8*)&s_At[b][mod][rowbase + mt*16 + lr][0]
                        : zf8;

    f32x4 hacc[2][2][2];                              // [batch][mt][nt] = H^T
    {
        bhalf8 wf[2];
        #pragma unroll
        for (int nt = 0; nt < 2; ++nt) {              // Wa-path init (K=8)
            wf[nt] = zf8;
            if (k8) {
                const float* p = wa + (nt*16 + lr) * 8;
                #pragma unroll
                for (int i = 0; i < 8; ++i) wf[nt][i] = f2bf(p[i]);
            }
        }
        #pragma unroll
        for (int b = 0; b < 2; ++b)
        #pragma unroll
        for (int mt = 0; mt < 2; ++mt)
        #pragma unroll
        for (int nt = 0; nt < 2; ++nt)
            hacc[b][mt][nt] = MFMA(wf[nt], atf[b][mt], zf4);
    }

    const int i0 = rowbase + lr;                      // mt=0 row
    const int i1 = rowbase + 16 + lr;                 // mt=1 row

    for (int cc = 0; cc < 8; ++cc) {                  // 8 chunks of 32 att-cols
        // Wca fragments for this chunk (L2; shared by both batches)
        bhalf8 bwc[2];
        #pragma unroll
        for (int nt = 0; nt < 2; ++nt)
            bwc[nt] = *(const bhalf8*)(wca + (nt*16 + lr)*256 + cc*32 + lg*8);

        f32x4 mT[2][2][2];                            // [batch][mt][nt] z^T frags
        #pragma unroll
        for (int nt = 0; nt < 2; ++nt) {
            bhalf8 gf0 = k8 ? *(const bhalf8*)(sG + ((0*2+mod)*256 + cc*32 + nt*16 + lr)*8) : zf8;
            bhalf8 gf1 = k8 ? *(const bhalf8*)(sG + ((1*2+mod)*256 + cc*32 + nt*16 + lr)*8) : zf8;
            #pragma unroll
            for (int mt = 0; mt < 2; ++mt) {
                mT[0][mt][nt] = MFMA(gf0, atf[0][mt], zf4);
                mT[1][mt][nt] = MFMA(gf1, atf[1][mt], zf4);
            }
        }
        // batch-sequential z round-trip on the shared stripe
        #pragma unroll
        for (int b = 0; b < 2; ++b) {
            WFENCE();   // prior z reads of this stripe complete before overwrite
            #pragma unroll
            for (int mt = 0; mt < 2; ++mt) {
                int ir = mt ? i1 : i0;
                #pragma unroll
                for (int nt = 0; nt < 2; ++nt) {
                    float v[4];
                    #pragma unroll
                    for (int r = 0; r < 4; ++r) {
                        float e = fexp2(mT[b][mt][nt][r]);          // prefolded
                        v[r] = fmaf(-2.0f, frcp(e + 1.0f), 1.0f);   // tanh
                    }
                    uint2v u;
                    u[0] = pk2bf(v[0], v[1]);
                    u[1] = pk2bf(v[2], v[3]);
                    *(uint2v*)(zs + ir*ZPITCH + nt*32 + lg*8) = u;
                }
            }
            WFENCE();   // z writes visible (wave-local) before reads
            bhalf8 az0 = *(const bhalf8*)(zs + i0*ZPITCH + lg*16);
            bhalf8 az1 = *(const bhalf8*)(zs + i1*ZPITCH + lg*16);
            #pragma unroll
            for (int nt = 0; nt < 2; ++nt) {
                hacc[b][0][nt] = MFMA(bwc[nt], az0, hacc[b][0][nt]);
                hacc[b][1][nt] = MFMA(bwc[nt], az1, hacc[b][1][nt]);
            }
        }
    }

    // H epilogue: batch-sequential on the same stripe
    bhalf8 whaf = zf8;                    // Wha B-frag (8 real cols, K=32 full)
    if (lr < 8) {
        const float* p = wha + lr*32 + lg*8;
        #pragma unroll
        for (int i = 0; i < 8; ++i) whaf[i] = f2bf(p[i]);
    }
    f4v wcf[2];
    #pragma unroll
    for (int mt = 0; mt < 2; ++mt)
        wcf[mt] = *(const f4v*)(wcomb + mod*128 + rowbase + mt*16 + lg*4);

    #pragma unroll
    for (int b = 0; b < 2; ++b) {
        WFENCE();       // prior stripe reads done before H overlay writes
        #pragma unroll
        for (int mt = 0; mt < 2; ++mt) {
            int ir = mt ? i1 : i0;
            #pragma unroll
            for (int nt = 0; nt < 2; ++nt) {
                uint2v u;
                u[0] = pk2bf(fmaxf(hacc[b][mt][nt][0], 0.f),
                             fmaxf(hacc[b][mt][nt][1], 0.f));
                u[1] = pk2bf(fmaxf(hacc[b][mt][nt][2], 0.f),
                             fmaxf(hacc[b][mt][nt][3], 0.f));
                *(uint2v*)(zs + ir*ZPITCH + nt*32 + lg*8) = u;
            }
        }
        WFENCE();
        #pragma unroll
        for (int mt = 0; mt < 2; ++mt) {
            int ir = mt ? i1 : i0;
            bhalf8 af = *(const bhalf8*)(zs + ir*ZPITCH + lg*16);
            f32x4 oa = MFMA(af, whaf, zf4);           // D[i-local][t'=lr]
            if (lr < 8) {
                #pragma unroll
                for (int r = 0; r < 4; ++r) {
                    int irow = rowbase + mt*16 + lg*4 + r;
                    float val = oa[r] + bf2f(s_At[b][mod][irow][lr]);
                    pacc[b] += val * wcf[mt][r];
                }
            }
        }
    }

    // reduce over lg (xor 16/32), then over 8 waves
    #pragma unroll
    for (int b = 0; b < 2; ++b) {
        pacc[b] += __shfl_xor(pacc[b], 16, 64);
        pacc[b] += __shfl_xor(pacc[b], 32, 64);
    }
    if (l < 8) { s_red[w][0][l] = pacc[0]; s_red[w][1][l] = pacc[1]; }
    __syncthreads();
    if (tid < 16) {
        int b = tid >> 3, t = tid & 7;
        float s = *(const float*)(ws + OFF_BC);
        #pragma unroll
        for (int q = 0; q < 8; ++q) s += s_red[q][b][t];
        out[((long)blockIdx.x * 2 + b) * 8 + t] = s;
    }
}

extern "C" void kernel_launch(void* const* d_in, const int* in_sizes, int n_in,
                              void* d_out, int out_size, void* d_ws, size_t ws_size,
                              hipStream_t stream)
{
    const float* f1    = (const float*)d_in[0];
    const float* f2    = (const float*)d_in[1];
    const float* We1   = (const float*)d_in[2];
    const float* be1   = (const float*)d_in[3];
    const float* We2   = (const float*)d_in[4];
    const float* be2   = (const float*)d_in[5];
    const float* Waffa = (const float*)d_in[6];
    const float* Waffv = (const float*)d_in[7];
    const float* Wa    = (const float*)d_in[8];
    const float* Wv    = (const float*)d_in[9];
    const float* Wca   = (const float*)d_in[10];
    const float* Wcv   = (const float*)d_in[11];
    const float* Wha   = (const float*)d_in[12];
    const float* Whv   = (const float*)d_in[13];
    const float* Wr1   = (const float*)d_in[14];
    const float* br1   = (const float*)d_in[15];
    const float* Wr2   = (const float*)d_in[16];
    const float* br2   = (const float*)d_in[17];
    char* ws = (char*)d_ws;
    float* out = (float*)d_out;

    k_prep <<<256,  256, 0, stream>>>(We1, We2, Wca, Wcv, Wr1, br1, Wr2, br2, ws);
    k_fused<<<2048, 512, 0, stream>>>(f1, f2, be1, be2, Waffa, Waffv,
                                      Wa, Wv, Wha, Whv, ws, out);
}